// Round 13
// baseline (566.142 us; speedup 1.0000x reference)
//
#include <hip/hip_runtime.h>
#include <hip/hip_bf16.h>
#include <cstdint>
#include <cstddef>

#define LN_EPS 1e-5f
#define B_    8
#define HW_   64
#define C_    256
#define NTOK  (B_ * HW_ * HW_)   // 32768
#define HEADS_ 8
#define DH_    32
#define NPATCH 15                // 15*15 = 225 patches per batch image

// ==================== ln_h: h = LN2(LN1(x)) precomputed (T1/T2) ====================
__global__ __launch_bounds__(256) void ln_h_kernel(
    const float* __restrict__ x, const float* __restrict__ g1,
    const float* __restrict__ b1, const float* __restrict__ g2,
    const float* __restrict__ b2, float* __restrict__ h)
{
    const int gid  = blockIdx.x * 256 + threadIdx.x;
    const int tok  = gid >> 6;
    const int lane = gid & 63;
    if (tok >= NTOK) return;
    const float4 xv = reinterpret_cast<const float4*>(x + (size_t)tok * C_)[lane];
    float s  = xv.x + xv.y + xv.z + xv.w;
    float sq = xv.x*xv.x + xv.y*xv.y + xv.z*xv.z + xv.w*xv.w;
    for (int off = 32; off; off >>= 1) {
        s  += __shfl_xor(s, off);
        sq += __shfl_xor(sq, off);
    }
    const float m1 = s * (1.0f / 256.0f);
    const float r1 = rsqrtf(fmaxf(sq * (1.0f / 256.0f) - m1 * m1, 0.0f) + LN_EPS);
    const float4 g = reinterpret_cast<const float4*>(g1)[lane];
    const float4 b = reinterpret_cast<const float4*>(b1)[lane];
    const float y0 = (xv.x - m1) * r1 * g.x + b.x;
    const float y1 = (xv.y - m1) * r1 * g.y + b.y;
    const float y2 = (xv.z - m1) * r1 * g.z + b.z;
    const float y3 = (xv.w - m1) * r1 * g.w + b.w;
    float s2  = y0 + y1 + y2 + y3;
    float sq2 = y0*y0 + y1*y1 + y2*y2 + y3*y3;
    for (int off = 32; off; off >>= 1) {
        s2  += __shfl_xor(s2, off);
        sq2 += __shfl_xor(sq2, off);
    }
    const float m2 = s2 * (1.0f / 256.0f);
    const float r2 = rsqrtf(fmaxf(sq2 * (1.0f / 256.0f) - m2 * m2, 0.0f) + LN_EPS);
    const float4 G = reinterpret_cast<const float4*>(g2)[lane];
    const float4 B = reinterpret_cast<const float4*>(b2)[lane];
    float4 hv;
    hv.x = (y0 - m2) * r2 * G.x + B.x;
    hv.y = (y1 - m2) * r2 * G.y + B.y;
    hv.z = (y2 - m2) * r2 * G.z + B.z;
    hv.w = (y3 - m2) * r2 * G.w + B.w;
    reinterpret_cast<float4*>(h + (size_t)tok * C_)[lane] = hv;
}

// ==================== qkv_h8: qkv = h @ w_qkv, 128x128 tile, 8x8 microtile ====================
__global__ __launch_bounds__(256) void qkv_h8_kernel(
    const float* __restrict__ h, const float* __restrict__ w, float* __restrict__ qkv)
{
    __shared__ float At[16][132];
    __shared__ float Bt[16][132];
    const int tid  = threadIdx.x;
    const int tok0 = blockIdx.y * 128;
    const int n0   = blockIdx.x * 128;
    const int ty = tid >> 4, tx = tid & 15;
    const int ar = tid >> 2, aseg = tid & 3;
    const int bk = tid >> 5, bn = tid & 31;
    const float* hrow0 = h + (size_t)(tok0 + ar) * C_;
    const float* hrow1 = h + (size_t)(tok0 + ar + 64) * C_;
    float acc[8][8] = {};
    for (int kk = 0; kk < 16; ++kk) {
        const int k0 = kk * 16;
        const float4 a0v = *reinterpret_cast<const float4*>(hrow0 + k0 + aseg * 4);
        const float4 a1v = *reinterpret_cast<const float4*>(hrow1 + k0 + aseg * 4);
        const float4 b0v = *reinterpret_cast<const float4*>(w + (size_t)(k0 + bk) * 768 + n0 + bn * 4);
        const float4 b1v = *reinterpret_cast<const float4*>(w + (size_t)(k0 + bk + 8) * 768 + n0 + bn * 4);
        __syncthreads();
        At[aseg*4+0][ar]    = a0v.x;
        At[aseg*4+1][ar]    = a0v.y;
        At[aseg*4+2][ar]    = a0v.z;
        At[aseg*4+3][ar]    = a0v.w;
        At[aseg*4+0][ar+64] = a1v.x;
        At[aseg*4+1][ar+64] = a1v.y;
        At[aseg*4+2][ar+64] = a1v.z;
        At[aseg*4+3][ar+64] = a1v.w;
        *reinterpret_cast<float4*>(&Bt[bk][bn*4])     = b0v;
        *reinterpret_cast<float4*>(&Bt[bk+8][bn*4])   = b1v;
        __syncthreads();
        #pragma unroll
        for (int k = 0; k < 16; ++k) {
            const float4 x0 = *reinterpret_cast<const float4*>(&At[k][ty*8]);
            const float4 x1 = *reinterpret_cast<const float4*>(&At[k][ty*8 + 4]);
            const float4 y0 = *reinterpret_cast<const float4*>(&Bt[k][tx*4]);
            const float4 y1 = *reinterpret_cast<const float4*>(&Bt[k][64 + tx*4]);
            const float a[8] = {x0.x, x0.y, x0.z, x0.w, x1.x, x1.y, x1.z, x1.w};
            const float b[8] = {y0.x, y0.y, y0.z, y0.w, y1.x, y1.y, y1.z, y1.w};
            #pragma unroll
            for (int i = 0; i < 8; ++i) {
                #pragma unroll
                for (int j = 0; j < 8; ++j)
                    acc[i][j] = fmaf(a[i], b[j], acc[i][j]);
            }
        }
    }
    #pragma unroll
    for (int i = 0; i < 8; ++i) {
        float* orow = qkv + (size_t)(tok0 + ty*8 + i) * 768 + n0;
        *reinterpret_cast<float4*>(orow + tx*4) =
            make_float4(acc[i][0], acc[i][1], acc[i][2], acc[i][3]);
        *reinterpret_cast<float4*>(orow + 64 + tx*4) =
            make_float4(acc[i][4], acc[i][5], acc[i][6], acc[i][7]);
    }
}

// ==================== T0 path: R6 verbatim (stats + fused-LN qkv) ====================
__global__ __launch_bounds__(256) void ln_stats_kernel(
    const float* __restrict__ x, const float* __restrict__ g1,
    const float* __restrict__ b1, float4* __restrict__ stats)
{
    const int gid  = blockIdx.x * 256 + threadIdx.x;
    const int tok  = gid >> 6;
    const int lane = gid & 63;
    if (tok >= NTOK) return;
    const float4 xv = reinterpret_cast<const float4*>(x + (size_t)tok * C_)[lane];
    float s  = xv.x + xv.y + xv.z + xv.w;
    float sq = xv.x*xv.x + xv.y*xv.y + xv.z*xv.z + xv.w*xv.w;
    for (int off = 32; off; off >>= 1) {
        s  += __shfl_xor(s, off);
        sq += __shfl_xor(sq, off);
    }
    const float m1 = s * (1.0f / 256.0f);
    const float r1 = rsqrtf(fmaxf(sq * (1.0f / 256.0f) - m1 * m1, 0.0f) + LN_EPS);
    const float4 g = reinterpret_cast<const float4*>(g1)[lane];
    const float4 b = reinterpret_cast<const float4*>(b1)[lane];
    const float y0 = (xv.x - m1) * r1 * g.x + b.x;
    const float y1 = (xv.y - m1) * r1 * g.y + b.y;
    const float y2 = (xv.z - m1) * r1 * g.z + b.z;
    const float y3 = (xv.w - m1) * r1 * g.w + b.w;
    float s2  = y0 + y1 + y2 + y3;
    float sq2 = y0*y0 + y1*y1 + y2*y2 + y3*y3;
    for (int off = 32; off; off >>= 1) {
        s2  += __shfl_xor(s2, off);
        sq2 += __shfl_xor(sq2, off);
    }
    const float m2 = s2 * (1.0f / 256.0f);
    const float r2 = rsqrtf(fmaxf(sq2 * (1.0f / 256.0f) - m2 * m2, 0.0f) + LN_EPS);
    if (lane == 0) stats[tok] = make_float4(m1, r1, m2, r2);
}

__global__ __launch_bounds__(256) void qkv_kernel(
    const float* __restrict__ x, const float4* __restrict__ stats,
    const float* __restrict__ g1, const float* __restrict__ b1,
    const float* __restrict__ g2, const float* __restrict__ b2,
    const float* __restrict__ w, float* __restrict__ qkv)
{
    __shared__ float At[16][72];
    __shared__ float Bt[16][64];
    const int tid  = threadIdx.x;
    const int tok0 = blockIdx.y * 64;
    const int n0   = blockIdx.x * 64;
    const int ty = tid >> 4, tx = tid & 15;
    const int st = tid >> 2, sseg = tid & 3;
    const int bk = tid >> 4, bx = tid & 15;
    const float4 s4 = stats[tok0 + st];
    const float* xrow = x + (size_t)(tok0 + st) * C_;
    float acc[4][4] = {};
    for (int kk = 0; kk < 16; ++kk) {
        const int k0 = kk * 16;
        const int ka = k0 + sseg * 4;
        const float4 xv  = *reinterpret_cast<const float4*>(xrow + ka);
        const float4 g1v = *reinterpret_cast<const float4*>(g1 + ka);
        const float4 b1v = *reinterpret_cast<const float4*>(b1 + ka);
        const float4 g2v = *reinterpret_cast<const float4*>(g2 + ka);
        const float4 b2v = *reinterpret_cast<const float4*>(b2 + ka);
        const float h0 = ((xv.x - s4.x)*s4.y*g1v.x + b1v.x - s4.z)*s4.w*g2v.x + b2v.x;
        const float h1 = ((xv.y - s4.x)*s4.y*g1v.y + b1v.y - s4.z)*s4.w*g2v.y + b2v.y;
        const float h2 = ((xv.z - s4.x)*s4.y*g1v.z + b1v.z - s4.z)*s4.w*g2v.z + b2v.z;
        const float h3 = ((xv.w - s4.x)*s4.y*g1v.w + b1v.w - s4.z)*s4.w*g2v.w + b2v.w;
        const float4 wv = *reinterpret_cast<const float4*>(w + (size_t)(k0 + bk) * 768 + n0 + bx * 4);
        __syncthreads();
        At[sseg*4+0][st] = h0;
        At[sseg*4+1][st] = h1;
        At[sseg*4+2][st] = h2;
        At[sseg*4+3][st] = h3;
        *reinterpret_cast<float4*>(&Bt[bk][bx*4]) = wv;
        __syncthreads();
        #pragma unroll
        for (int k = 0; k < 16; ++k) {
            const float4 a = *reinterpret_cast<const float4*>(&At[k][ty*4]);
            const float4 b = *reinterpret_cast<const float4*>(&Bt[k][tx*4]);
            acc[0][0] += a.x*b.x; acc[0][1] += a.x*b.y; acc[0][2] += a.x*b.z; acc[0][3] += a.x*b.w;
            acc[1][0] += a.y*b.x; acc[1][1] += a.y*b.y; acc[1][2] += a.y*b.z; acc[1][3] += a.y*b.w;
            acc[2][0] += a.z*b.x; acc[2][1] += a.z*b.y; acc[2][2] += a.z*b.z; acc[2][3] += a.z*b.w;
            acc[3][0] += a.w*b.x; acc[3][1] += a.w*b.y; acc[3][2] += a.w*b.z; acc[3][3] += a.w*b.w;
        }
    }
    #pragma unroll
    for (int r = 0; r < 4; ++r) {
        const float4 o = make_float4(acc[r][0], acc[r][1], acc[r][2], acc[r][3]);
        *reinterpret_cast<float4*>(qkv + (size_t)(tok0 + ty*4 + r) * 768 + n0 + tx*4) = o;
    }
}

// ==================== attn_flash (T2): wave = (patch, head); lane = query row ====================
// Per block: patch x 4 heads (wave wid = head hg*4+wid). Wave-private K/V in LDS
// ([64][33]: compute reads are same-address broadcasts -> conflict-free). q/o in
// registers (static indices only). Online softmax with defer-max THR=8 (T13):
// no p storage, no shuffles, no cross-wave coupling; one barrier post-staging.
__global__ __launch_bounds__(256) void attn_flash_kernel(
    const float* __restrict__ qkv, float* __restrict__ obuf)
{
    __shared__ float kbuf[4][64][33];   // 33.8 KB
    __shared__ float vbuf[4][64][33];   // 33.8 KB  -> total 67.6 KB, 2 blocks/CU
    const int tid  = threadIdx.x;
    const int wid  = tid >> 6;          // wave -> head within group
    const int lane = tid & 63;          // lane -> query row (token in patch)
    const int b    = blockIdx.y;
    const int hg   = blockIdx.z;        // head group 0/1
    const int hd   = hg * 4 + wid;
    const int pi   = blockIdx.x / NPATCH;
    const int pj   = blockIdx.x % NPATCH;
    const int rowbase = (b * 64 + 4*pi) * 64 + 4*pj;   // pixel of patch token (0,0)

    // ---- stage K,V for this wave's head: iter i covers patch-rows pr=i ----
    {
        const int pc = lane >> 3, f4 = lane & 7;   // 8 pixels x 8 float4-chunks
        #pragma unroll
        for (int i = 0; i < 8; ++i) {
            const size_t pix = (size_t)rowbase + i * 64 + pc;
            const float* src = qkv + pix * 768 + hd * 32 + f4 * 4;
            const float4 kv4 = *reinterpret_cast<const float4*>(src + 256);
            const float4 vv4 = *reinterpret_cast<const float4*>(src + 512);
            *reinterpret_cast<float4*>(&kbuf[wid][i*8 + pc][f4*4]) = kv4;
            *reinterpret_cast<float4*>(&vbuf[wid][i*8 + pc][f4*4]) = vv4;
        }
    }
    // ---- q row for this lane -> registers (scale folded in) ----
    const float scale = 0.17677669529663687f;  // 32^-0.5
    const int qpr = lane >> 3, qpc = lane & 7;
    const float* qsrc = qkv + ((size_t)rowbase + qpr * 64 + qpc) * 768 + hd * 32;
    float4 q4[8];
    #pragma unroll
    for (int u = 0; u < 8; ++u) {
        float4 qv = *reinterpret_cast<const float4*>(qsrc + u * 4);
        qv.x *= scale; qv.y *= scale; qv.z *= scale; qv.w *= scale;
        q4[u] = qv;
    }
    __syncthreads();   // staging visible (cheap safety; single barrier per block)

    // ---- fused QK + online-softmax + PV (defer-max THR=8) ----
    float m = -1.0e30f, l = 0.0f;
    float4 o4[8];
    #pragma unroll
    for (int u = 0; u < 8; ++u) o4[u] = make_float4(0.f, 0.f, 0.f, 0.f);

    for (int jc = 0; jc < 64; ++jc) {
        float a0 = 0.f, a1 = 0.f, a2 = 0.f, a3 = 0.f;
        #pragma unroll
        for (int u = 0; u < 8; ++u) {
            const float4 kv = *reinterpret_cast<const float4*>(&kbuf[wid][jc][u*4]);
            a0 = fmaf(q4[u].x, kv.x, a0);
            a1 = fmaf(q4[u].y, kv.y, a1);
            a2 = fmaf(q4[u].z, kv.z, a2);
            a3 = fmaf(q4[u].w, kv.w, a3);
        }
        const float s = (a0 + a1) + (a2 + a3);
        if (s > m + 8.0f) {                    // rare rescale (exec-masked)
            const float f = __expf(m - s);
            m = s;
            l *= f;
            #pragma unroll
            for (int u = 0; u < 8; ++u) {
                o4[u].x *= f; o4[u].y *= f; o4[u].z *= f; o4[u].w *= f;
            }
        }
        const float p = __expf(s - m);
        l += p;
        #pragma unroll
        for (int u = 0; u < 8; ++u) {
            const float4 vv = *reinterpret_cast<const float4*>(&vbuf[wid][jc][u*4]);
            o4[u].x = fmaf(p, vv.x, o4[u].x);
            o4[u].y = fmaf(p, vv.y, o4[u].y);
            o4[u].z = fmaf(p, vv.z, o4[u].z);
            o4[u].w = fmaf(p, vv.w, o4[u].w);
        }
    }
    const float rl = 1.0f / l;
    float* op = obuf + ((size_t)(b * 225 + pi * NPATCH + pj) * 64 + lane) * 256 + hd * 32;
    #pragma unroll
    for (int u = 0; u < 8; ++u) {
        *reinterpret_cast<float4*>(op + u * 4) =
            make_float4(o4[u].x * rl, o4[u].y * rl, o4[u].z * rl, o4[u].w * rl);
    }
}

// ==================== attn (T0/T1): 4-group RMW path (known-pass) ====================
__global__ __launch_bounds__(256) void attn_kernel(
    const float* __restrict__ qkv, float* __restrict__ out,
    int gi, int gj, int nJ, int do_store)
{
    __shared__ float smem[6784];
    float (*q_lds)[36] = reinterpret_cast<float(*)[36]>(smem);
    float (*kT)[68]    = reinterpret_cast<float(*)[68]>(smem + 2304);
    float (*v_lds)[36] = reinterpret_cast<float(*)[36]>(smem + 4480);
    float (*p_lds)[67] = reinterpret_cast<float(*)[67]>(smem);
    const int tid = threadIdx.x;
    const int b  = blockIdx.y;
    const int hd = blockIdx.z;
    const int pi = 2 * (blockIdx.x / nJ) + gi;
    const int pj = 2 * (blockIdx.x % nJ) + gj;
    const int t = tid >> 2, seg = tid & 3;
    const int pr = t >> 3, pc = t & 7;
    const size_t pixbase = ((size_t)((b * 64 + 4*pi + pr) * 64) + (4*pj + pc));
    {
        const size_t base = pixbase * 768 + hd * 32 + seg * 8;
        const float4 qa = *reinterpret_cast<const float4*>(qkv + base);
        const float4 qb = *reinterpret_cast<const float4*>(qkv + base + 4);
        const float4 ka = *reinterpret_cast<const float4*>(qkv + base + 256);
        const float4 kb = *reinterpret_cast<const float4*>(qkv + base + 260);
        const float4 va = *reinterpret_cast<const float4*>(qkv + base + 512);
        const float4 vb = *reinterpret_cast<const float4*>(qkv + base + 516);
        *reinterpret_cast<float4*>(&q_lds[t][seg*8    ]) = qa;
        *reinterpret_cast<float4*>(&q_lds[t][seg*8 + 4]) = qb;
        *reinterpret_cast<float4*>(&v_lds[t][seg*8    ]) = va;
        *reinterpret_cast<float4*>(&v_lds[t][seg*8 + 4]) = vb;
        const int d0 = seg * 8;
        kT[d0+0][t] = ka.x; kT[d0+1][t] = ka.y; kT[d0+2][t] = ka.z; kT[d0+3][t] = ka.w;
        kT[d0+4][t] = kb.x; kT[d0+5][t] = kb.y; kT[d0+6][t] = kb.z; kT[d0+7][t] = kb.w;
    }
    __syncthreads();
    const float scale = 0.17677669529663687f;
    const int tr = tid >> 4, tc = tid & 15;
    float s[4][4] = {};
    #pragma unroll
    for (int kk = 0; kk < 4; ++kk) {
        float qreg[4][8];
        #pragma unroll
        for (int i = 0; i < 4; ++i) {
            const float4 qv0 = *reinterpret_cast<const float4*>(&q_lds[tr*4 + i][kk*8]);
            const float4 qv1 = *reinterpret_cast<const float4*>(&q_lds[tr*4 + i][kk*8 + 4]);
            qreg[i][0] = qv0.x; qreg[i][1] = qv0.y; qreg[i][2] = qv0.z; qreg[i][3] = qv0.w;
            qreg[i][4] = qv1.x; qreg[i][5] = qv1.y; qreg[i][6] = qv1.z; qreg[i][7] = qv1.w;
        }
        #pragma unroll
        for (int w = 0; w < 8; ++w) {
            const float4 kv = *reinterpret_cast<const float4*>(&kT[kk*8 + w][tc*4]);
            const float ka[4] = {kv.x, kv.y, kv.z, kv.w};
            #pragma unroll
            for (int i = 0; i < 4; ++i) {
                #pragma unroll
                for (int j = 0; j < 4; ++j)
                    s[i][j] = fmaf(qreg[i][w], ka[j], s[i][j]);
            }
        }
    }
    float mrow[4], sum[4];
    #pragma unroll
    for (int i = 0; i < 4; ++i) {
        s[i][0] *= scale; s[i][1] *= scale; s[i][2] *= scale; s[i][3] *= scale;
        mrow[i] = fmaxf(fmaxf(s[i][0], s[i][1]), fmaxf(s[i][2], s[i][3]));
    }
    #pragma unroll
    for (int off = 1; off < 16; off <<= 1)
        #pragma unroll
        for (int i = 0; i < 4; ++i)
            mrow[i] = fmaxf(mrow[i], __shfl_xor(mrow[i], off));
    #pragma unroll
    for (int i = 0; i < 4; ++i) {
        sum[i] = 0.f;
        #pragma unroll
        for (int j = 0; j < 4; ++j) {
            s[i][j] = __expf(s[i][j] - mrow[i]);
            sum[i] += s[i][j];
        }
    }
    #pragma unroll
    for (int off = 1; off < 16; off <<= 1)
        #pragma unroll
        for (int i = 0; i < 4; ++i)
            sum[i] += __shfl_xor(sum[i], off);
    __syncthreads();
    #pragma unroll
    for (int i = 0; i < 4; ++i) {
        const float rs = 1.0f / sum[i];
        #pragma unroll
        for (int j = 0; j < 4; ++j)
            p_lds[tr*4 + i][tc*4 + j] = s[i][j] * rs;
    }
    __syncthreads();
    float4 o0 = make_float4(0,0,0,0), o1 = make_float4(0,0,0,0);
    for (int jc = 0; jc < 64; ++jc) {
        const float a = p_lds[t][jc];
        const float4 v0 = *reinterpret_cast<const float4*>(&v_lds[jc][seg*8]);
        const float4 v1 = *reinterpret_cast<const float4*>(&v_lds[jc][seg*8 + 4]);
        o0.x = fmaf(a, v0.x, o0.x); o0.y = fmaf(a, v0.y, o0.y);
        o0.z = fmaf(a, v0.z, o0.z); o0.w = fmaf(a, v0.w, o0.w);
        o1.x = fmaf(a, v1.x, o1.x); o1.y = fmaf(a, v1.y, o1.y);
        o1.z = fmaf(a, v1.z, o1.z); o1.w = fmaf(a, v1.w, o1.w);
    }
    float* op = out + pixbase * 256 + hd * 32 + seg * 8;
    if (do_store) {
        *reinterpret_cast<float4*>(op)     = o0;
        *reinterpret_cast<float4*>(op + 4) = o1;
    } else {
        float4 c0 = *reinterpret_cast<const float4*>(op);
        float4 c1 = *reinterpret_cast<const float4*>(op + 4);
        c0.x += o0.x; c0.y += o0.y; c0.z += o0.z; c0.w += o0.w;
        c1.x += o1.x; c1.y += o1.y; c1.z += o1.z; c1.w += o1.w;
        *reinterpret_cast<float4*>(op)     = c0;
        *reinterpret_cast<float4*>(op + 4) = c1;
    }
}

// ==================== projection ====================
__global__ __launch_bounds__(256) void proj_gather_kernel(
    const float* __restrict__ obuf, const float* __restrict__ w,
    const float* __restrict__ bo, float* __restrict__ out)
{
    __shared__ float At[16][36];
    __shared__ float Bt[16][256];
    const int tid  = threadIdx.x;
    const int tok0 = blockIdx.x * 32;
    const int ty = tid >> 5, tx = tid & 31;
    const int st = tid >> 2, sseg = tid & 3;
    const int bc = (tid & 63) * 4, bkb = tid >> 6;
    const float* s00 = obuf; const float* s01 = obuf;
    const float* s10 = obuf; const float* s11 = obuf;
    if (tid < 128) {
        const int token = tok0 + st;
        const int bb = token >> 12;
        const int hp = (token >> 6) & 63, wp = token & 63;
        const int pil = (hp >= 4) ? ((hp - 4) >> 2) : 0;
        const int pih = (hp >> 2) > 14 ? 14 : (hp >> 2);
        const int pjl = (wp >= 4) ? ((wp - 4) >> 2) : 0;
        const int pjh = (wp >> 2) > 14 ? 14 : (wp >> 2);
        const size_t base_b = (size_t)bb * 225;
        s00 = obuf + ((base_b + pil * NPATCH + pjl) * 64 + (8*(hp-4*pil) + (wp-4*pjl))) * 256;
        s01 = obuf + ((base_b + pil * NPATCH + pjh) * 64 + (8*(hp-4*pil) + (wp-4*pjh))) * 256;
        s10 = obuf + ((base_b + pih * NPATCH + pjl) * 64 + (8*(hp-4*pih) + (wp-4*pjl))) * 256;
        s11 = obuf + ((base_b + pih * NPATCH + pjh) * 64 + (8*(hp-4*pih) + (wp-4*pjh))) * 256;
    }
    float acc[4][8] = {};
    for (int kk = 0; kk < 16; ++kk) {
        const int k0 = kk * 16;
        float4 av = make_float4(0,0,0,0);
        if (tid < 128) {
            const int off = k0 + sseg * 4;
            const float4 v0 = *reinterpret_cast<const float4*>(s00 + off);
            const float4 v1 = *reinterpret_cast<const float4*>(s01 + off);
            const float4 v2 = *reinterpret_cast<const float4*>(s10 + off);
            const float4 v3 = *reinterpret_cast<const float4*>(s11 + off);
            av.x = ((v0.x + v1.x) + (v2.x + v3.x)) * 0.25f;
            av.y = ((v0.y + v1.y) + (v2.y + v3.y)) * 0.25f;
            av.z = ((v0.z + v1.z) + (v2.z + v3.z)) * 0.25f;
            av.w = ((v0.w + v1.w) + (v2.w + v3.w)) * 0.25f;
        }
        float4 wv[4];
        #pragma unroll
        for (int u = 0; u < 4; ++u)
            wv[u] = *reinterpret_cast<const float4*>(w + (size_t)(k0 + bkb*4 + u) * 256 + bc);
        __syncthreads();
        if (tid < 128) {
            At[sseg*4+0][st] = av.x;
            At[sseg*4+1][st] = av.y;
            At[sseg*4+2][st] = av.z;
            At[sseg*4+3][st] = av.w;
        }
        #pragma unroll
        for (int u = 0; u < 4; ++u)
            *reinterpret_cast<float4*>(&Bt[bkb*4+u][bc]) = wv[u];
        __syncthreads();
        #pragma unroll
        for (int k = 0; k < 16; ++k) {
            const float4 a  = *reinterpret_cast<const float4*>(&At[k][ty*4]);
            const float4 b0 = *reinterpret_cast<const float4*>(&Bt[k][tx*4]);
            const float4 b1 = *reinterpret_cast<const float4*>(&Bt[k][128 + tx*4]);
            acc[0][0] += a.x*b0.x; acc[0][1] += a.x*b0.y; acc[0][2] += a.x*b0.z; acc[0][3] += a.x*b0.w;
            acc[0][4] += a.x*b1.x; acc[0][5] += a.x*b1.y; acc[0][6] += a.x*b1.z; acc[0][7] += a.x*b1.w;
            acc[1][0] += a.y*b0.x; acc[1][1] += a.y*b0.y; acc[1][2] += a.y*b0.z; acc[1][3] += a.y*b0.w;
            acc[1][4] += a.y*b1.x; acc[1][5] += a.y*b1.y; acc[1][6] += a.y*b1.z; acc[1][7] += a.y*b1.w;
            acc[2][0] += a.z*b0.x; acc[2][1] += a.z*b0.y; acc[2][2] += a.z*b0.z; acc[2][3] += a.z*b0.w;
            acc[2][4] += a.z*b1.x; acc[2][5] += a.z*b1.y; acc[2][6] += a.z*b1.z; acc[2][7] += a.z*b1.w;
            acc[3][0] += a.w*b0.x; acc[3][1] += a.w*b0.y; acc[3][2] += a.w*b0.z; acc[3][3] += a.w*b0.w;
            acc[3][4] += a.w*b1.x; acc[3][5] += a.w*b1.y; acc[3][6] += a.w*b1.z; acc[3][7] += a.w*b1.w;
        }
    }
    const float4 bo0 = *reinterpret_cast<const float4*>(bo + tx*4);
    const float4 bo1 = *reinterpret_cast<const float4*>(bo + 128 + tx*4);
    #pragma unroll
    for (int r = 0; r < 4; ++r) {
        float* orow = out + (size_t)(tok0 + ty*4 + r) * 256;
        const float4 o0 = make_float4(acc[r][0]+bo0.x, acc[r][1]+bo0.y, acc[r][2]+bo0.z, acc[r][3]+bo0.w);
        const float4 o1 = make_float4(acc[r][4]+bo1.x, acc[r][5]+bo1.y, acc[r][6]+bo1.z, acc[r][7]+bo1.w);
        *reinterpret_cast<float4*>(orow + tx*4)       = o0;
        *reinterpret_cast<float4*>(orow + 128 + tx*4) = o1;
    }
}

__global__ __launch_bounds__(256) void proj_kernel(
    float* __restrict__ out, const float* __restrict__ w, const float* __restrict__ bo)
{
    __shared__ float At[16][36];
    __shared__ float Bt[16][256];
    const int tid  = threadIdx.x;
    const int tok0 = blockIdx.x * 32;
    const int ty = tid >> 5, tx = tid & 31;
    const int st = tid >> 2, sseg = tid & 3;
    const int bc = (tid & 63) * 4, bkb = tid >> 6;
    float ascale = 0.f;
    if (tid < 128) {
        const int token = tok0 + st;
        const int hp = (token >> 6) & 63, wp = token & 63;
        const float cnt = ((hp >= 4 && hp < 60) ? 2.f : 1.f) * ((wp >= 4 && wp < 60) ? 2.f : 1.f);
        ascale = 1.0f / cnt;
    }
    float acc[4][8] = {};
    for (int kk = 0; kk < 16; ++kk) {
        const int k0 = kk * 16;
        float4 av = make_float4(0,0,0,0);
        if (tid < 128)
            av = *reinterpret_cast<const float4*>(out + (size_t)(tok0 + st) * 256 + k0 + sseg * 4);
        float4 wv[4];
        #pragma unroll
        for (int u = 0; u < 4; ++u)
            wv[u] = *reinterpret_cast<const float4*>(w + (size_t)(k0 + bkb*4 + u) * 256 + bc);
        __syncthreads();
        if (tid < 128) {
            At[sseg*4+0][st] = av.x * ascale;
            At[sseg*4+1][st] = av.y * ascale;
            At[sseg*4+2][st] = av.z * ascale;
            At[sseg*4+3][st] = av.w * ascale;
        }
        #pragma unroll
        for (int u = 0; u < 4; ++u)
            *reinterpret_cast<float4*>(&Bt[bkb*4+u][bc]) = wv[u];
        __syncthreads();
        #pragma unroll
        for (int k = 0; k < 16; ++k) {
            const float4 a  = *reinterpret_cast<const float4*>(&At[k][ty*4]);
            const float4 b0 = *reinterpret_cast<const float4*>(&Bt[k][tx*4]);
            const float4 b1 = *reinterpret_cast<const float4*>(&Bt[k][128 + tx*4]);
            acc[0][0] += a.x*b0.x; acc[0][1] += a.x*b0.y; acc[0][2] += a.x*b0.z; acc[0][3] += a.x*b0.w;
            acc[0][4] += a.x*b1.x; acc[0][5] += a.x*b1.y; acc[0][6] += a.x*b1.z; acc[0][7] += a.x*b1.w;
            acc[1][0] += a.y*b0.x; acc[1][1] += a.y*b0.y; acc[1][2] += a.y*b0.z; acc[1][3] += a.y*b0.w;
            acc[1][4] += a.y*b1.x; acc[1][5] += a.y*b1.y; acc[1][6] += a.y*b1.z; acc[1][7] += a.y*b1.w;
            acc[2][0] += a.z*b0.x; acc[2][1] += a.z*b0.y; acc[2][2] += a.z*b0.z; acc[2][3] += a.z*b0.w;
            acc[2][4] += a.z*b1.x; acc[2][5] += a.z*b1.y; acc[2][6] += a.z*b1.z; acc[2][7] += a.z*b1.w;
            acc[3][0] += a.w*b0.x; acc[3][1] += a.w*b0.y; acc[3][2] += a.w*b0.z; acc[3][3] += a.w*b0.w;
            acc[3][4] += a.w*b1.x; acc[3][5] += a.w*b1.y; acc[3][6] += a.w*b1.z; acc[3][7] += a.w*b1.w;
        }
    }
    const float4 bo0 = *reinterpret_cast<const float4*>(bo + tx*4);
    const float4 bo1 = *reinterpret_cast<const float4*>(bo + 128 + tx*4);
    #pragma unroll
    for (int r = 0; r < 4; ++r) {
        float* orow = out + (size_t)(tok0 + ty*4 + r) * 256;
        const float4 o0 = make_float4(acc[r][0]+bo0.x, acc[r][1]+bo0.y, acc[r][2]+bo0.z, acc[r][3]+bo0.w);
        const float4 o1 = make_float4(acc[r][4]+bo1.x, acc[r][5]+bo1.y, acc[r][6]+bo1.z, acc[r][7]+bo1.w);
        *reinterpret_cast<float4*>(orow + tx*4)       = o0;
        *reinterpret_cast<float4*>(orow + 128 + tx*4) = o1;
    }
}

extern "C" void kernel_launch(void* const* d_in, const int* in_sizes, int n_in,
                              void* d_out, int out_size, void* d_ws, size_t ws_size,
                              hipStream_t stream)
{
    const float* x     = (const float*)d_in[0];
    const float* ln1_g = (const float*)d_in[1];
    const float* ln1_b = (const float*)d_in[2];
    const float* ln2_g = (const float*)d_in[3];
    const float* ln2_b = (const float*)d_in[4];
    const float* w_qkv = (const float*)d_in[5];
    const float* w_out = (const float*)d_in[6];
    const float* b_out = (const float*)d_in[7];
    float* out = (float*)d_out;
    char*  ws  = (char*)d_ws;

    const size_t h_b    = (size_t)NTOK * C_ * 4;             // 32 MB
    const size_t qkv_b  = (size_t)NTOK * 768 * 4;            // 96 MB
    const size_t obuf_b = (size_t)B_ * 225 * 64 * 256 * 4;   // 112.5 MB
    const size_t stats_b = (size_t)NTOK * 16;                // 512 KB

    if (ws_size >= h_b + qkv_b) {
        float* h    = (float*)ws;
        float* qkv  = (float*)(ws + h_b);
        float* obuf = (float*)(ws + h_b + qkv_b);
        ln_h_kernel<<<NTOK / 4, 256, 0, stream>>>(x, ln1_g, ln1_b, ln2_g, ln2_b, h);
        qkv_h8_kernel<<<dim3(6, NTOK / 128), 256, 0, stream>>>(h, w_qkv, qkv);
        if (ws_size >= h_b + qkv_b + obuf_b) {
            // T2: flash attn (wave = patch x head) + gather-proj
            attn_flash_kernel<<<dim3(225, B_, 2), 256, 0, stream>>>(qkv, obuf);
            proj_gather_kernel<<<NTOK / 32, 256, 0, stream>>>(obuf, w_out, b_out, out);
        } else {
            // T1: 4-group RMW attn + in-place proj
            for (int g = 0; g < 4; ++g) {
                const int gi = g >> 1, gj = g & 1;
                const int nI = gi ? 7 : 8, nJ = gj ? 7 : 8;
                attn_kernel<<<dim3(nI * nJ, B_, HEADS_), 256, 0, stream>>>(
                    qkv, out, gi, gj, nJ, (g == 0) ? 1 : 0);
            }
            proj_kernel<<<NTOK / 32, 256, 0, stream>>>(out, w_out, b_out);
        }
    } else {
        // T0: R6 verbatim
        float4* stats = (float4*)ws;
        float*  qkv   = (float*)(ws + stats_b);
        ln_stats_kernel<<<NTOK / 4, 256, 0, stream>>>(x, ln1_g, ln1_b, stats);
        qkv_kernel<<<dim3(12, NTOK / 64), 256, 0, stream>>>(
            x, stats, ln1_g, ln1_b, ln2_g, ln2_b, w_qkv, qkv);
        for (int g = 0; g < 4; ++g) {
            const int gi = g >> 1, gj = g & 1;
            const int nI = gi ? 7 : 8, nJ = gj ? 7 : 8;
            attn_kernel<<<dim3(nI * nJ, B_, HEADS_), 256, 0, stream>>>(
                qkv, out, gi, gj, nJ, (g == 0) ? 1 : 0);
        }
        proj_kernel<<<NTOK / 32, 256, 0, stream>>>(out, w_out, b_out);
    }
}

// Round 14
// 401.005 us; speedup vs baseline: 1.4118x; 1.4118x over previous
//
#include <hip/hip_runtime.h>
#include <hip/hip_bf16.h>
#include <cstdint>
#include <cstddef>

#define LN_EPS 1e-5f
#define B_    8
#define HW_   64
#define C_    256
#define NTOK  (B_ * HW_ * HW_)   // 32768
#define HEADS_ 8
#define DH_    32
#define NPATCH 15                // 15*15 = 225 patches per batch image

// ==================== ln_h: h = LN2(LN1(x)) precomputed (T1/T2) ====================
__global__ __launch_bounds__(256) void ln_h_kernel(
    const float* __restrict__ x, const float* __restrict__ g1,
    const float* __restrict__ b1, const float* __restrict__ g2,
    const float* __restrict__ b2, float* __restrict__ h)
{
    const int gid  = blockIdx.x * 256 + threadIdx.x;
    const int tok  = gid >> 6;
    const int lane = gid & 63;
    if (tok >= NTOK) return;
    const float4 xv = reinterpret_cast<const float4*>(x + (size_t)tok * C_)[lane];
    float s  = xv.x + xv.y + xv.z + xv.w;
    float sq = xv.x*xv.x + xv.y*xv.y + xv.z*xv.z + xv.w*xv.w;
    for (int off = 32; off; off >>= 1) {
        s  += __shfl_xor(s, off);
        sq += __shfl_xor(sq, off);
    }
    const float m1 = s * (1.0f / 256.0f);
    const float r1 = rsqrtf(fmaxf(sq * (1.0f / 256.0f) - m1 * m1, 0.0f) + LN_EPS);
    const float4 g = reinterpret_cast<const float4*>(g1)[lane];
    const float4 b = reinterpret_cast<const float4*>(b1)[lane];
    const float y0 = (xv.x - m1) * r1 * g.x + b.x;
    const float y1 = (xv.y - m1) * r1 * g.y + b.y;
    const float y2 = (xv.z - m1) * r1 * g.z + b.z;
    const float y3 = (xv.w - m1) * r1 * g.w + b.w;
    float s2  = y0 + y1 + y2 + y3;
    float sq2 = y0*y0 + y1*y1 + y2*y2 + y3*y3;
    for (int off = 32; off; off >>= 1) {
        s2  += __shfl_xor(s2, off);
        sq2 += __shfl_xor(sq2, off);
    }
    const float m2 = s2 * (1.0f / 256.0f);
    const float r2 = rsqrtf(fmaxf(sq2 * (1.0f / 256.0f) - m2 * m2, 0.0f) + LN_EPS);
    const float4 G = reinterpret_cast<const float4*>(g2)[lane];
    const float4 B = reinterpret_cast<const float4*>(b2)[lane];
    float4 hv;
    hv.x = (y0 - m2) * r2 * G.x + B.x;
    hv.y = (y1 - m2) * r2 * G.y + B.y;
    hv.z = (y2 - m2) * r2 * G.z + B.z;
    hv.w = (y3 - m2) * r2 * G.w + B.w;
    reinterpret_cast<float4*>(h + (size_t)tok * C_)[lane] = hv;
}

// ==================== qkv_h8: qkv = h @ w_qkv, 128x128 tile, 8x8 microtile ====================
__global__ __launch_bounds__(256) void qkv_h8_kernel(
    const float* __restrict__ h, const float* __restrict__ w, float* __restrict__ qkv)
{
    __shared__ float At[16][132];
    __shared__ float Bt[16][132];
    const int tid  = threadIdx.x;
    const int tok0 = blockIdx.y * 128;
    const int n0   = blockIdx.x * 128;
    const int ty = tid >> 4, tx = tid & 15;
    const int ar = tid >> 2, aseg = tid & 3;
    const int bk = tid >> 5, bn = tid & 31;
    const float* hrow0 = h + (size_t)(tok0 + ar) * C_;
    const float* hrow1 = h + (size_t)(tok0 + ar + 64) * C_;
    float acc[8][8] = {};
    for (int kk = 0; kk < 16; ++kk) {
        const int k0 = kk * 16;
        const float4 a0v = *reinterpret_cast<const float4*>(hrow0 + k0 + aseg * 4);
        const float4 a1v = *reinterpret_cast<const float4*>(hrow1 + k0 + aseg * 4);
        const float4 b0v = *reinterpret_cast<const float4*>(w + (size_t)(k0 + bk) * 768 + n0 + bn * 4);
        const float4 b1v = *reinterpret_cast<const float4*>(w + (size_t)(k0 + bk + 8) * 768 + n0 + bn * 4);
        __syncthreads();
        At[aseg*4+0][ar]    = a0v.x;
        At[aseg*4+1][ar]    = a0v.y;
        At[aseg*4+2][ar]    = a0v.z;
        At[aseg*4+3][ar]    = a0v.w;
        At[aseg*4+0][ar+64] = a1v.x;
        At[aseg*4+1][ar+64] = a1v.y;
        At[aseg*4+2][ar+64] = a1v.z;
        At[aseg*4+3][ar+64] = a1v.w;
        *reinterpret_cast<float4*>(&Bt[bk][bn*4])     = b0v;
        *reinterpret_cast<float4*>(&Bt[bk+8][bn*4])   = b1v;
        __syncthreads();
        #pragma unroll
        for (int k = 0; k < 16; ++k) {
            const float4 x0 = *reinterpret_cast<const float4*>(&At[k][ty*8]);
            const float4 x1 = *reinterpret_cast<const float4*>(&At[k][ty*8 + 4]);
            const float4 y0 = *reinterpret_cast<const float4*>(&Bt[k][tx*4]);
            const float4 y1 = *reinterpret_cast<const float4*>(&Bt[k][64 + tx*4]);
            const float a[8] = {x0.x, x0.y, x0.z, x0.w, x1.x, x1.y, x1.z, x1.w};
            const float b[8] = {y0.x, y0.y, y0.z, y0.w, y1.x, y1.y, y1.z, y1.w};
            #pragma unroll
            for (int i = 0; i < 8; ++i) {
                #pragma unroll
                for (int j = 0; j < 8; ++j)
                    acc[i][j] = fmaf(a[i], b[j], acc[i][j]);
            }
        }
    }
    #pragma unroll
    for (int i = 0; i < 8; ++i) {
        float* orow = qkv + (size_t)(tok0 + ty*8 + i) * 768 + n0;
        *reinterpret_cast<float4*>(orow + tx*4) =
            make_float4(acc[i][0], acc[i][1], acc[i][2], acc[i][3]);
        *reinterpret_cast<float4*>(orow + 64 + tx*4) =
            make_float4(acc[i][4], acc[i][5], acc[i][6], acc[i][7]);
    }
}

// ==================== T0 path: R6 verbatim (stats + fused-LN qkv) ====================
__global__ __launch_bounds__(256) void ln_stats_kernel(
    const float* __restrict__ x, const float* __restrict__ g1,
    const float* __restrict__ b1, float4* __restrict__ stats)
{
    const int gid  = blockIdx.x * 256 + threadIdx.x;
    const int tok  = gid >> 6;
    const int lane = gid & 63;
    if (tok >= NTOK) return;
    const float4 xv = reinterpret_cast<const float4*>(x + (size_t)tok * C_)[lane];
    float s  = xv.x + xv.y + xv.z + xv.w;
    float sq = xv.x*xv.x + xv.y*xv.y + xv.z*xv.z + xv.w*xv.w;
    for (int off = 32; off; off >>= 1) {
        s  += __shfl_xor(s, off);
        sq += __shfl_xor(sq, off);
    }
    const float m1 = s * (1.0f / 256.0f);
    const float r1 = rsqrtf(fmaxf(sq * (1.0f / 256.0f) - m1 * m1, 0.0f) + LN_EPS);
    const float4 g = reinterpret_cast<const float4*>(g1)[lane];
    const float4 b = reinterpret_cast<const float4*>(b1)[lane];
    const float y0 = (xv.x - m1) * r1 * g.x + b.x;
    const float y1 = (xv.y - m1) * r1 * g.y + b.y;
    const float y2 = (xv.z - m1) * r1 * g.z + b.z;
    const float y3 = (xv.w - m1) * r1 * g.w + b.w;
    float s2  = y0 + y1 + y2 + y3;
    float sq2 = y0*y0 + y1*y1 + y2*y2 + y3*y3;
    for (int off = 32; off; off >>= 1) {
        s2  += __shfl_xor(s2, off);
        sq2 += __shfl_xor(sq2, off);
    }
    const float m2 = s2 * (1.0f / 256.0f);
    const float r2 = rsqrtf(fmaxf(sq2 * (1.0f / 256.0f) - m2 * m2, 0.0f) + LN_EPS);
    if (lane == 0) stats[tok] = make_float4(m1, r1, m2, r2);
}

__global__ __launch_bounds__(256) void qkv_kernel(
    const float* __restrict__ x, const float4* __restrict__ stats,
    const float* __restrict__ g1, const float* __restrict__ b1,
    const float* __restrict__ g2, const float* __restrict__ b2,
    const float* __restrict__ w, float* __restrict__ qkv)
{
    __shared__ float At[16][72];
    __shared__ float Bt[16][64];
    const int tid  = threadIdx.x;
    const int tok0 = blockIdx.y * 64;
    const int n0   = blockIdx.x * 64;
    const int ty = tid >> 4, tx = tid & 15;
    const int st = tid >> 2, sseg = tid & 3;
    const int bk = tid >> 4, bx = tid & 15;
    const float4 s4 = stats[tok0 + st];
    const float* xrow = x + (size_t)(tok0 + st) * C_;
    float acc[4][4] = {};
    for (int kk = 0; kk < 16; ++kk) {
        const int k0 = kk * 16;
        const int ka = k0 + sseg * 4;
        const float4 xv  = *reinterpret_cast<const float4*>(xrow + ka);
        const float4 g1v = *reinterpret_cast<const float4*>(g1 + ka);
        const float4 b1v = *reinterpret_cast<const float4*>(b1 + ka);
        const float4 g2v = *reinterpret_cast<const float4*>(g2 + ka);
        const float4 b2v = *reinterpret_cast<const float4*>(b2 + ka);
        const float h0 = ((xv.x - s4.x)*s4.y*g1v.x + b1v.x - s4.z)*s4.w*g2v.x + b2v.x;
        const float h1 = ((xv.y - s4.x)*s4.y*g1v.y + b1v.y - s4.z)*s4.w*g2v.y + b2v.y;
        const float h2 = ((xv.z - s4.x)*s4.y*g1v.z + b1v.z - s4.z)*s4.w*g2v.z + b2v.z;
        const float h3 = ((xv.w - s4.x)*s4.y*g1v.w + b1v.w - s4.z)*s4.w*g2v.w + b2v.w;
        const float4 wv = *reinterpret_cast<const float4*>(w + (size_t)(k0 + bk) * 768 + n0 + bx * 4);
        __syncthreads();
        At[sseg*4+0][st] = h0;
        At[sseg*4+1][st] = h1;
        At[sseg*4+2][st] = h2;
        At[sseg*4+3][st] = h3;
        *reinterpret_cast<float4*>(&Bt[bk][bx*4]) = wv;
        __syncthreads();
        #pragma unroll
        for (int k = 0; k < 16; ++k) {
            const float4 a = *reinterpret_cast<const float4*>(&At[k][ty*4]);
            const float4 b = *reinterpret_cast<const float4*>(&Bt[k][tx*4]);
            acc[0][0] += a.x*b.x; acc[0][1] += a.x*b.y; acc[0][2] += a.x*b.z; acc[0][3] += a.x*b.w;
            acc[1][0] += a.y*b.x; acc[1][1] += a.y*b.y; acc[1][2] += a.y*b.z; acc[1][3] += a.y*b.w;
            acc[2][0] += a.z*b.x; acc[2][1] += a.z*b.y; acc[2][2] += a.z*b.z; acc[2][3] += a.z*b.w;
            acc[3][0] += a.w*b.x; acc[3][1] += a.w*b.y; acc[3][2] += a.w*b.z; acc[3][3] += a.w*b.w;
        }
    }
    #pragma unroll
    for (int r = 0; r < 4; ++r) {
        const float4 o = make_float4(acc[r][0], acc[r][1], acc[r][2], acc[r][3]);
        *reinterpret_cast<float4*>(qkv + (size_t)(tok0 + ty*4 + r) * 768 + n0 + tx*4) = o;
    }
}

// ==================== attn_o (T2, R12-proven): per (patch, head), writes obuf ====================
__global__ __launch_bounds__(256) void attn_o_kernel(
    const float* __restrict__ qkv, float* __restrict__ obuf)
{
    __shared__ float smem[6784];   // q[64][36] | kT[32][68] | v[64][36]; p overlays q+kT
    float (*q_lds)[36] = reinterpret_cast<float(*)[36]>(smem);
    float (*kT)[68]    = reinterpret_cast<float(*)[68]>(smem + 2304);
    float (*v_lds)[36] = reinterpret_cast<float(*)[36]>(smem + 4480);
    float (*p_lds)[67] = reinterpret_cast<float(*)[67]>(smem);
    const int tid = threadIdx.x;
    const int b  = blockIdx.y;
    const int hd = blockIdx.z;
    const int pi = blockIdx.x / NPATCH;
    const int pj = blockIdx.x % NPATCH;
    const int t = tid >> 2, seg = tid & 3;
    const int pr = t >> 3, pc = t & 7;
    const size_t pixbase = ((size_t)((b * 64 + 4*pi + pr) * 64) + (4*pj + pc));
    {
        const size_t base = pixbase * 768 + hd * 32 + seg * 8;
        const float4 qa = *reinterpret_cast<const float4*>(qkv + base);
        const float4 qb = *reinterpret_cast<const float4*>(qkv + base + 4);
        const float4 ka = *reinterpret_cast<const float4*>(qkv + base + 256);
        const float4 kb = *reinterpret_cast<const float4*>(qkv + base + 260);
        const float4 va = *reinterpret_cast<const float4*>(qkv + base + 512);
        const float4 vb = *reinterpret_cast<const float4*>(qkv + base + 516);
        *reinterpret_cast<float4*>(&q_lds[t][seg*8    ]) = qa;
        *reinterpret_cast<float4*>(&q_lds[t][seg*8 + 4]) = qb;
        *reinterpret_cast<float4*>(&v_lds[t][seg*8    ]) = va;
        *reinterpret_cast<float4*>(&v_lds[t][seg*8 + 4]) = vb;
        const int d0 = seg * 8;
        kT[d0+0][t] = ka.x; kT[d0+1][t] = ka.y; kT[d0+2][t] = ka.z; kT[d0+3][t] = ka.w;
        kT[d0+4][t] = kb.x; kT[d0+5][t] = kb.y; kT[d0+6][t] = kb.z; kT[d0+7][t] = kb.w;
    }
    __syncthreads();
    const float scale = 0.17677669529663687f;  // 32^-0.5
    const int tr = tid >> 4, tc = tid & 15;
    float s[4][4] = {};
    #pragma unroll
    for (int kk = 0; kk < 4; ++kk) {
        float qreg[4][8];
        #pragma unroll
        for (int i = 0; i < 4; ++i) {
            const float4 qv0 = *reinterpret_cast<const float4*>(&q_lds[tr*4 + i][kk*8]);
            const float4 qv1 = *reinterpret_cast<const float4*>(&q_lds[tr*4 + i][kk*8 + 4]);
            qreg[i][0] = qv0.x; qreg[i][1] = qv0.y; qreg[i][2] = qv0.z; qreg[i][3] = qv0.w;
            qreg[i][4] = qv1.x; qreg[i][5] = qv1.y; qreg[i][6] = qv1.z; qreg[i][7] = qv1.w;
        }
        #pragma unroll
        for (int w = 0; w < 8; ++w) {
            const float4 kv = *reinterpret_cast<const float4*>(&kT[kk*8 + w][tc*4]);
            const float ka[4] = {kv.x, kv.y, kv.z, kv.w};
            #pragma unroll
            for (int i = 0; i < 4; ++i) {
                #pragma unroll
                for (int j = 0; j < 4; ++j)
                    s[i][j] = fmaf(qreg[i][w], ka[j], s[i][j]);
            }
        }
    }
    float mrow[4], sum[4];
    #pragma unroll
    for (int i = 0; i < 4; ++i) {
        s[i][0] *= scale; s[i][1] *= scale; s[i][2] *= scale; s[i][3] *= scale;
        mrow[i] = fmaxf(fmaxf(s[i][0], s[i][1]), fmaxf(s[i][2], s[i][3]));
    }
    #pragma unroll
    for (int off = 1; off < 16; off <<= 1)
        #pragma unroll
        for (int i = 0; i < 4; ++i)
            mrow[i] = fmaxf(mrow[i], __shfl_xor(mrow[i], off));
    #pragma unroll
    for (int i = 0; i < 4; ++i) {
        sum[i] = 0.f;
        #pragma unroll
        for (int j = 0; j < 4; ++j) {
            s[i][j] = __expf(s[i][j] - mrow[i]);
            sum[i] += s[i][j];
        }
    }
    #pragma unroll
    for (int off = 1; off < 16; off <<= 1)
        #pragma unroll
        for (int i = 0; i < 4; ++i)
            sum[i] += __shfl_xor(sum[i], off);
    __syncthreads();   // all QK reads of q/kT complete before p overwrites them
    #pragma unroll
    for (int i = 0; i < 4; ++i) {
        const float rs = 1.0f / sum[i];
        #pragma unroll
        for (int j = 0; j < 4; ++j)
            p_lds[tr*4 + i][tc*4 + j] = s[i][j] * rs;
    }
    __syncthreads();
    float4 o0 = make_float4(0,0,0,0), o1 = make_float4(0,0,0,0);
    for (int jc = 0; jc < 64; ++jc) {
        const float a = p_lds[t][jc];
        const float4 v0 = *reinterpret_cast<const float4*>(&v_lds[jc][seg*8]);
        const float4 v1 = *reinterpret_cast<const float4*>(&v_lds[jc][seg*8 + 4]);
        o0.x = fmaf(a, v0.x, o0.x); o0.y = fmaf(a, v0.y, o0.y);
        o0.z = fmaf(a, v0.z, o0.z); o0.w = fmaf(a, v0.w, o0.w);
        o1.x = fmaf(a, v1.x, o1.x); o1.y = fmaf(a, v1.y, o1.y);
        o1.z = fmaf(a, v1.z, o1.z); o1.w = fmaf(a, v1.w, o1.w);
    }
    float* op = obuf + ((size_t)(b * 225 + pi * NPATCH + pj) * 64 + t) * 256 + hd * 32 + seg * 8;
    *reinterpret_cast<float4*>(op)     = o0;
    *reinterpret_cast<float4*>(op + 4) = o1;
}

// ==================== attn (T0/T1): 4-group RMW path (known-pass) ====================
__global__ __launch_bounds__(256) void attn_kernel(
    const float* __restrict__ qkv, float* __restrict__ out,
    int gi, int gj, int nJ, int do_store)
{
    __shared__ float smem[6784];
    float (*q_lds)[36] = reinterpret_cast<float(*)[36]>(smem);
    float (*kT)[68]    = reinterpret_cast<float(*)[68]>(smem + 2304);
    float (*v_lds)[36] = reinterpret_cast<float(*)[36]>(smem + 4480);
    float (*p_lds)[67] = reinterpret_cast<float(*)[67]>(smem);
    const int tid = threadIdx.x;
    const int b  = blockIdx.y;
    const int hd = blockIdx.z;
    const int pi = 2 * (blockIdx.x / nJ) + gi;
    const int pj = 2 * (blockIdx.x % nJ) + gj;
    const int t = tid >> 2, seg = tid & 3;
    const int pr = t >> 3, pc = t & 7;
    const size_t pixbase = ((size_t)((b * 64 + 4*pi + pr) * 64) + (4*pj + pc));
    {
        const size_t base = pixbase * 768 + hd * 32 + seg * 8;
        const float4 qa = *reinterpret_cast<const float4*>(qkv + base);
        const float4 qb = *reinterpret_cast<const float4*>(qkv + base + 4);
        const float4 ka = *reinterpret_cast<const float4*>(qkv + base + 256);
        const float4 kb = *reinterpret_cast<const float4*>(qkv + base + 260);
        const float4 va = *reinterpret_cast<const float4*>(qkv + base + 512);
        const float4 vb = *reinterpret_cast<const float4*>(qkv + base + 516);
        *reinterpret_cast<float4*>(&q_lds[t][seg*8    ]) = qa;
        *reinterpret_cast<float4*>(&q_lds[t][seg*8 + 4]) = qb;
        *reinterpret_cast<float4*>(&v_lds[t][seg*8    ]) = va;
        *reinterpret_cast<float4*>(&v_lds[t][seg*8 + 4]) = vb;
        const int d0 = seg * 8;
        kT[d0+0][t] = ka.x; kT[d0+1][t] = ka.y; kT[d0+2][t] = ka.z; kT[d0+3][t] = ka.w;
        kT[d0+4][t] = kb.x; kT[d0+5][t] = kb.y; kT[d0+6][t] = kb.z; kT[d0+7][t] = kb.w;
    }
    __syncthreads();
    const float scale = 0.17677669529663687f;
    const int tr = tid >> 4, tc = tid & 15;
    float s[4][4] = {};
    #pragma unroll
    for (int kk = 0; kk < 4; ++kk) {
        float qreg[4][8];
        #pragma unroll
        for (int i = 0; i < 4; ++i) {
            const float4 qv0 = *reinterpret_cast<const float4*>(&q_lds[tr*4 + i][kk*8]);
            const float4 qv1 = *reinterpret_cast<const float4*>(&q_lds[tr*4 + i][kk*8 + 4]);
            qreg[i][0] = qv0.x; qreg[i][1] = qv0.y; qreg[i][2] = qv0.z; qreg[i][3] = qv0.w;
            qreg[i][4] = qv1.x; qreg[i][5] = qv1.y; qreg[i][6] = qv1.z; qreg[i][7] = qv1.w;
        }
        #pragma unroll
        for (int w = 0; w < 8; ++w) {
            const float4 kv = *reinterpret_cast<const float4*>(&kT[kk*8 + w][tc*4]);
            const float ka[4] = {kv.x, kv.y, kv.z, kv.w};
            #pragma unroll
            for (int i = 0; i < 4; ++i) {
                #pragma unroll
                for (int j = 0; j < 4; ++j)
                    s[i][j] = fmaf(qreg[i][w], ka[j], s[i][j]);
            }
        }
    }
    float mrow[4], sum[4];
    #pragma unroll
    for (int i = 0; i < 4; ++i) {
        s[i][0] *= scale; s[i][1] *= scale; s[i][2] *= scale; s[i][3] *= scale;
        mrow[i] = fmaxf(fmaxf(s[i][0], s[i][1]), fmaxf(s[i][2], s[i][3]));
    }
    #pragma unroll
    for (int off = 1; off < 16; off <<= 1)
        #pragma unroll
        for (int i = 0; i < 4; ++i)
            mrow[i] = fmaxf(mrow[i], __shfl_xor(mrow[i], off));
    #pragma unroll
    for (int i = 0; i < 4; ++i) {
        sum[i] = 0.f;
        #pragma unroll
        for (int j = 0; j < 4; ++j) {
            s[i][j] = __expf(s[i][j] - mrow[i]);
            sum[i] += s[i][j];
        }
    }
    #pragma unroll
    for (int off = 1; off < 16; off <<= 1)
        #pragma unroll
        for (int i = 0; i < 4; ++i)
            sum[i] += __shfl_xor(sum[i], off);
    __syncthreads();
    #pragma unroll
    for (int i = 0; i < 4; ++i) {
        const float rs = 1.0f / sum[i];
        #pragma unroll
        for (int j = 0; j < 4; ++j)
            p_lds[tr*4 + i][tc*4 + j] = s[i][j] * rs;
    }
    __syncthreads();
    float4 o0 = make_float4(0,0,0,0), o1 = make_float4(0,0,0,0);
    for (int jc = 0; jc < 64; ++jc) {
        const float a = p_lds[t][jc];
        const float4 v0 = *reinterpret_cast<const float4*>(&v_lds[jc][seg*8]);
        const float4 v1 = *reinterpret_cast<const float4*>(&v_lds[jc][seg*8 + 4]);
        o0.x = fmaf(a, v0.x, o0.x); o0.y = fmaf(a, v0.y, o0.y);
        o0.z = fmaf(a, v0.z, o0.z); o0.w = fmaf(a, v0.w, o0.w);
        o1.x = fmaf(a, v1.x, o1.x); o1.y = fmaf(a, v1.y, o1.y);
        o1.z = fmaf(a, v1.z, o1.z); o1.w = fmaf(a, v1.w, o1.w);
    }
    float* op = out + pixbase * 256 + hd * 32 + seg * 8;
    if (do_store) {
        *reinterpret_cast<float4*>(op)     = o0;
        *reinterpret_cast<float4*>(op + 4) = o1;
    } else {
        float4 c0 = *reinterpret_cast<const float4*>(op);
        float4 c1 = *reinterpret_cast<const float4*>(op + 4);
        c0.x += o0.x; c0.y += o0.y; c0.z += o0.z; c0.w += o0.w;
        c1.x += o1.x; c1.y += o1.y; c1.z += o1.z; c1.w += o1.w;
        *reinterpret_cast<float4*>(op)     = c0;
        *reinterpret_cast<float4*>(op + 4) = c1;
    }
}

// ==================== gather: A[token] = 0.25 * sum of 4 clamped patch rows ====================
// Grid 8192 x 256: 64 consecutive threads cover one token's 64 float4 chunks (coalesced).
__global__ __launch_bounds__(256) void gather_kernel(
    const float* __restrict__ obuf, float* __restrict__ A)
{
    const int tid   = threadIdx.x;
    const int token = blockIdx.x * 4 + (tid >> 6);
    const int chunk = tid & 63;
    const int bb = token >> 12;
    const int hp = (token >> 6) & 63, wp = token & 63;
    const int pil = (hp >= 4) ? ((hp - 4) >> 2) : 0;
    const int pih = (hp >> 2) > 14 ? 14 : (hp >> 2);
    const int pjl = (wp >= 4) ? ((wp - 4) >> 2) : 0;
    const int pjh = (wp >> 2) > 14 ? 14 : (wp >> 2);
    const size_t base_b = (size_t)bb * 225;
    const float* s00 = obuf + ((base_b + pil * NPATCH + pjl) * 64 + (8*(hp-4*pil) + (wp-4*pjl))) * 256;
    const float* s01 = obuf + ((base_b + pil * NPATCH + pjh) * 64 + (8*(hp-4*pil) + (wp-4*pjh))) * 256;
    const float* s10 = obuf + ((base_b + pih * NPATCH + pjl) * 64 + (8*(hp-4*pih) + (wp-4*pjl))) * 256;
    const float* s11 = obuf + ((base_b + pih * NPATCH + pjh) * 64 + (8*(hp-4*pih) + (wp-4*pjh))) * 256;
    const int off = chunk * 4;
    const float4 v0 = *reinterpret_cast<const float4*>(s00 + off);
    const float4 v1 = *reinterpret_cast<const float4*>(s01 + off);
    const float4 v2 = *reinterpret_cast<const float4*>(s10 + off);
    const float4 v3 = *reinterpret_cast<const float4*>(s11 + off);
    float4 a;
    a.x = ((v0.x + v1.x) + (v2.x + v3.x)) * 0.25f;
    a.y = ((v0.y + v1.y) + (v2.y + v3.y)) * 0.25f;
    a.z = ((v0.z + v1.z) + (v2.z + v3.z)) * 0.25f;
    a.w = ((v0.w + v1.w) + (v2.w + v3.w)) * 0.25f;
    *reinterpret_cast<float4*>(A + (size_t)token * 256 + off) = a;
}

// ==================== proj8: out = A @ w_out + b_out (qkv_h8 structure, N=256) ====================
__global__ __launch_bounds__(256) void proj8_kernel(
    const float* __restrict__ A, const float* __restrict__ w,
    const float* __restrict__ bo, float* __restrict__ out)
{
    __shared__ float At[16][132];
    __shared__ float Bt[16][132];
    const int tid  = threadIdx.x;
    const int tok0 = blockIdx.y * 128;
    const int n0   = blockIdx.x * 128;
    const int ty = tid >> 4, tx = tid & 15;
    const int ar = tid >> 2, aseg = tid & 3;
    const int bk = tid >> 5, bn = tid & 31;
    const float* arow0 = A + (size_t)(tok0 + ar) * 256;
    const float* arow1 = A + (size_t)(tok0 + ar + 64) * 256;
    float acc[8][8] = {};
    for (int kk = 0; kk < 16; ++kk) {
        const int k0 = kk * 16;
        const float4 a0v = *reinterpret_cast<const float4*>(arow0 + k0 + aseg * 4);
        const float4 a1v = *reinterpret_cast<const float4*>(arow1 + k0 + aseg * 4);
        const float4 b0v = *reinterpret_cast<const float4*>(w + (size_t)(k0 + bk) * 256 + n0 + bn * 4);
        const float4 b1v = *reinterpret_cast<const float4*>(w + (size_t)(k0 + bk + 8) * 256 + n0 + bn * 4);
        __syncthreads();
        At[aseg*4+0][ar]    = a0v.x;
        At[aseg*4+1][ar]    = a0v.y;
        At[aseg*4+2][ar]    = a0v.z;
        At[aseg*4+3][ar]    = a0v.w;
        At[aseg*4+0][ar+64] = a1v.x;
        At[aseg*4+1][ar+64] = a1v.y;
        At[aseg*4+2][ar+64] = a1v.z;
        At[aseg*4+3][ar+64] = a1v.w;
        *reinterpret_cast<float4*>(&Bt[bk][bn*4])   = b0v;
        *reinterpret_cast<float4*>(&Bt[bk+8][bn*4]) = b1v;
        __syncthreads();
        #pragma unroll
        for (int k = 0; k < 16; ++k) {
            const float4 x0 = *reinterpret_cast<const float4*>(&At[k][ty*8]);
            const float4 x1 = *reinterpret_cast<const float4*>(&At[k][ty*8 + 4]);
            const float4 y0 = *reinterpret_cast<const float4*>(&Bt[k][tx*4]);
            const float4 y1 = *reinterpret_cast<const float4*>(&Bt[k][64 + tx*4]);
            const float a[8] = {x0.x, x0.y, x0.z, x0.w, x1.x, x1.y, x1.z, x1.w};
            const float b[8] = {y0.x, y0.y, y0.z, y0.w, y1.x, y1.y, y1.z, y1.w};
            #pragma unroll
            for (int i = 0; i < 8; ++i) {
                #pragma unroll
                for (int j = 0; j < 8; ++j)
                    acc[i][j] = fmaf(a[i], b[j], acc[i][j]);
            }
        }
    }
    const float4 bo0 = *reinterpret_cast<const float4*>(bo + n0 + tx*4);
    const float4 bo1 = *reinterpret_cast<const float4*>(bo + n0 + 64 + tx*4);
    #pragma unroll
    for (int i = 0; i < 8; ++i) {
        float* orow = out + (size_t)(tok0 + ty*8 + i) * 256 + n0;
        *reinterpret_cast<float4*>(orow + tx*4) =
            make_float4(acc[i][0]+bo0.x, acc[i][1]+bo0.y, acc[i][2]+bo0.z, acc[i][3]+bo0.w);
        *reinterpret_cast<float4*>(orow + 64 + tx*4) =
            make_float4(acc[i][4]+bo1.x, acc[i][5]+bo1.y, acc[i][6]+bo1.z, acc[i][7]+bo1.w);
    }
}

// proj (T0/T1): out = (acc / counts) @ w_out + b_out, in-place.
__global__ __launch_bounds__(256) void proj_kernel(
    float* __restrict__ out, const float* __restrict__ w, const float* __restrict__ bo)
{
    __shared__ float At[16][36];
    __shared__ float Bt[16][256];
    const int tid  = threadIdx.x;
    const int tok0 = blockIdx.x * 32;
    const int ty = tid >> 5, tx = tid & 31;
    const int st = tid >> 2, sseg = tid & 3;
    const int bc = (tid & 63) * 4, bkb = tid >> 6;
    float ascale = 0.f;
    if (tid < 128) {
        const int token = tok0 + st;
        const int hp = (token >> 6) & 63, wp = token & 63;
        const float cnt = ((hp >= 4 && hp < 60) ? 2.f : 1.f) * ((wp >= 4 && wp < 60) ? 2.f : 1.f);
        ascale = 1.0f / cnt;
    }
    float acc[4][8] = {};
    for (int kk = 0; kk < 16; ++kk) {
        const int k0 = kk * 16;
        float4 av = make_float4(0,0,0,0);
        if (tid < 128)
            av = *reinterpret_cast<const float4*>(out + (size_t)(tok0 + st) * 256 + k0 + sseg * 4);
        float4 wv[4];
        #pragma unroll
        for (int u = 0; u < 4; ++u)
            wv[u] = *reinterpret_cast<const float4*>(w + (size_t)(k0 + bkb*4 + u) * 256 + bc);
        __syncthreads();
        if (tid < 128) {
            At[sseg*4+0][st] = av.x * ascale;
            At[sseg*4+1][st] = av.y * ascale;
            At[sseg*4+2][st] = av.z * ascale;
            At[sseg*4+3][st] = av.w * ascale;
        }
        #pragma unroll
        for (int u = 0; u < 4; ++u)
            *reinterpret_cast<float4*>(&Bt[bkb*4+u][bc]) = wv[u];
        __syncthreads();
        #pragma unroll
        for (int k = 0; k < 16; ++k) {
            const float4 a  = *reinterpret_cast<const float4*>(&At[k][ty*4]);
            const float4 b0 = *reinterpret_cast<const float4*>(&Bt[k][tx*4]);
            const float4 b1 = *reinterpret_cast<const float4*>(&Bt[k][128 + tx*4]);
            acc[0][0] += a.x*b0.x; acc[0][1] += a.x*b0.y; acc[0][2] += a.x*b0.z; acc[0][3] += a.x*b0.w;
            acc[0][4] += a.x*b1.x; acc[0][5] += a.x*b1.y; acc[0][6] += a.x*b1.z; acc[0][7] += a.x*b1.w;
            acc[1][0] += a.y*b0.x; acc[1][1] += a.y*b0.y; acc[1][2] += a.y*b0.z; acc[1][3] += a.y*b0.w;
            acc[1][4] += a.y*b1.x; acc[1][5] += a.y*b1.y; acc[1][6] += a.y*b1.z; acc[1][7] += a.y*b1.w;
            acc[2][0] += a.z*b0.x; acc[2][1] += a.z*b0.y; acc[2][2] += a.z*b0.z; acc[2][3] += a.z*b0.w;
            acc[2][4] += a.z*b1.x; acc[2][5] += a.z*b1.y; acc[2][6] += a.z*b1.z; acc[2][7] += a.z*b1.w;
            acc[3][0] += a.w*b0.x; acc[3][1] += a.w*b0.y; acc[3][2] += a.w*b0.z; acc[3][3] += a.w*b0.w;
            acc[3][4] += a.w*b1.x; acc[3][5] += a.w*b1.y; acc[3][6] += a.w*b1.z; acc[3][7] += a.w*b1.w;
        }
    }
    const float4 bo0 = *reinterpret_cast<const float4*>(bo + tx*4);
    const float4 bo1 = *reinterpret_cast<const float4*>(bo + 128 + tx*4);
    #pragma unroll
    for (int r = 0; r < 4; ++r) {
        float* orow = out + (size_t)(tok0 + ty*4 + r) * 256;
        const float4 o0 = make_float4(acc[r][0]+bo0.x, acc[r][1]+bo0.y, acc[r][2]+bo0.z, acc[r][3]+bo0.w);
        const float4 o1 = make_float4(acc[r][4]+bo1.x, acc[r][5]+bo1.y, acc[r][6]+bo1.z, acc[r][7]+bo1.w);
        *reinterpret_cast<float4*>(orow + tx*4)       = o0;
        *reinterpret_cast<float4*>(orow + 128 + tx*4) = o1;
    }
}

extern "C" void kernel_launch(void* const* d_in, const int* in_sizes, int n_in,
                              void* d_out, int out_size, void* d_ws, size_t ws_size,
                              hipStream_t stream)
{
    const float* x     = (const float*)d_in[0];
    const float* ln1_g = (const float*)d_in[1];
    const float* ln1_b = (const float*)d_in[2];
    const float* ln2_g = (const float*)d_in[3];
    const float* ln2_b = (const float*)d_in[4];
    const float* w_qkv = (const float*)d_in[5];
    const float* w_out = (const float*)d_in[6];
    const float* b_out = (const float*)d_in[7];
    float* out = (float*)d_out;
    char*  ws  = (char*)d_ws;

    const size_t h_b    = (size_t)NTOK * C_ * 4;             // 32 MB (reused as A after qkv)
    const size_t qkv_b  = (size_t)NTOK * 768 * 4;            // 96 MB
    const size_t obuf_b = (size_t)B_ * 225 * 64 * 256 * 4;   // 112.5 MB
    const size_t stats_b = (size_t)NTOK * 16;                // 512 KB

    if (ws_size >= h_b + qkv_b) {
        float* h    = (float*)ws;                  // h buffer; dead after qkv -> reused as A
        float* qkv  = (float*)(ws + h_b);
        float* obuf = (float*)(ws + h_b + qkv_b);
        ln_h_kernel<<<NTOK / 4, 256, 0, stream>>>(x, ln1_g, ln1_b, ln2_g, ln2_b, h);
        qkv_h8_kernel<<<dim3(6, NTOK / 128), 256, 0, stream>>>(h, w_qkv, qkv);
        if (ws_size >= h_b + qkv_b + obuf_b) {
            // T2: single attn launch -> obuf; gather into A (= h region); 8x8 proj GEMM
            attn_o_kernel<<<dim3(225, B_, HEADS_), 256, 0, stream>>>(qkv, obuf);
            gather_kernel<<<NTOK / 4, 256, 0, stream>>>(obuf, h);
            proj8_kernel<<<dim3(2, NTOK / 128), 256, 0, stream>>>(h, w_out, b_out, out);
        } else {
            // T1: 4-group RMW attn + in-place proj
            for (int g = 0; g < 4; ++g) {
                const int gi = g >> 1, gj = g & 1;
                const int nI = gi ? 7 : 8, nJ = gj ? 7 : 8;
                attn_kernel<<<dim3(nI * nJ, B_, HEADS_), 256, 0, stream>>>(
                    qkv, out, gi, gj, nJ, (g == 0) ? 1 : 0);
            }
            proj_kernel<<<NTOK / 32, 256, 0, stream>>>(out, w_out, b_out);
        }
    } else {
        // T0: R6 verbatim
        float4* stats = (float4*)ws;
        float*  qkv   = (float*)(ws + stats_b);
        ln_stats_kernel<<<NTOK / 4, 256, 0, stream>>>(x, ln1_g, ln1_b, stats);
        qkv_kernel<<<dim3(12, NTOK / 64), 256, 0, stream>>>(
            x, stats, ln1_g, ln1_b, ln2_g, ln2_b, w_qkv, qkv);
        for (int g = 0; g < 4; ++g) {
            const int gi = g >> 1, gj = g & 1;
            const int nI = gi ? 7 : 8, nJ = gj ? 7 : 8;
            attn_kernel<<<dim3(nI * nJ, B_, HEADS_), 256, 0, stream>>>(
                qkv, out, gi, gj, nJ, (g == 0) ? 1 : 0);
        }
        proj_kernel<<<NTOK / 32, 256, 0, stream>>>(out, w_out, b_out);
    }
}